// Round 1
// baseline (401.575 us; speedup 1.0000x reference)
//
#include <hip/hip_runtime.h>

#define B 2
#define L 2048
#define C 256
#define H 8
#define D 32
#define HB (H * B)
#define SCALE 0.17677669529663687f  // 1/sqrt(32)

// ---------------------------------------------------------------------------
// Kernel 1: projections.  grid = B*L/16 = 256 blocks, 256 threads.
// Each block handles 16 rows of (B*L); thread t owns output column t of Q/K.
// Q is scaled by 1/sqrt(D) here so passes A/B need no extra multiply.
// ---------------------------------------------------------------------------
__global__ __launch_bounds__(256) void proj_kernel(
    const float* __restrict__ x,   // (B,L,C)
    const float* __restrict__ Wq,  // (C, H*D)
    const float* __restrict__ bq,  // (H,1,1,D) flat = h*D+d
    const float* __restrict__ Wk,
    const float* __restrict__ bk,
    const float* __restrict__ Wv,  // (C, H)
    const float* __restrict__ pe,  // (L, C)
    float* __restrict__ Qo,        // (H,B,L,D)
    float* __restrict__ Ko,        // (H,B,L,D)
    float* __restrict__ Vo)        // (H,B,L)
{
    __shared__ float xq[16][C];
    __shared__ float xr[16][C];
    const int t = threadIdx.x;
    const int row0 = blockIdx.x * 16;

    for (int i = 0; i < 16; ++i) {
        const int row = row0 + i;
        const int l = row & (L - 1);
        const float xv = x[row * C + t];
        xr[i][t] = xv;
        xq[i][t] = xv + pe[l * C + t];
    }
    __syncthreads();

    float accq[16], acck[16];
#pragma unroll
    for (int i = 0; i < 16; ++i) { accq[i] = 0.f; acck[i] = 0.f; }

    for (int c = 0; c < C; ++c) {
        const float wq = Wq[c * (H * D) + t];
        const float wk = Wk[c * (H * D) + t];
#pragma unroll
        for (int i = 0; i < 16; ++i) {
            const float xv = xq[i][c];
            accq[i] += xv * wq;
            acck[i] += xv * wk;
        }
    }

    const int h = t >> 5, d = t & 31;
    const float bqv = bq[t];
    const float bkv = bk[t];
#pragma unroll
    for (int i = 0; i < 16; ++i) {
        const int row = row0 + i;
        const int b = row >> 11;       // row / L
        const int l = row & (L - 1);
        const int o = ((h * B + b) * L + l) * D + d;
        Qo[o] = (accq[i] + bqv) * SCALE;
        Ko[o] = acck[i] + bkv;
    }

    // V: 128 threads, thread = r*8 + h2
    if (t < 128) {
        const int r = t >> 3, h2 = t & 7;
        float acc = 0.f;
        for (int c = 0; c < C; ++c) acc += xr[r][c] * Wv[c * H + h2];
        const int row = row0 + r;
        const int b = row >> 11;
        const int l = row & (L - 1);
        Vo[(h2 * B + b) * L + l] = acc;
    }
}

// ---------------------------------------------------------------------------
// Kernel 2 (pass A): per-query softmax denominator l_q = sum_k exp(s_qk);
// stores G[q] = V[q] / l_q.
// grid = HB * (L/64) = 512 blocks, 256 threads = 4 waves.
// Wave kg handles key range [kg*512, kg*512+512); lane qi owns query qb*64+qi.
// LDS K tiles are read at wave-uniform addresses -> broadcast, conflict-free.
// ---------------------------------------------------------------------------
__global__ __launch_bounds__(256) void passA_kernel(
    const float* __restrict__ Q,
    const float* __restrict__ K,
    const float* __restrict__ V,
    float* __restrict__ G)
{
    __shared__ float kt[4][64][D];   // 32 KiB
    __shared__ float lred[4][64];
    const int tid = threadIdx.x;
    const int kg = tid >> 6, qi = tid & 63;
    const int hb = blockIdx.x >> 5;
    const int qb = blockIdx.x & 31;
    const int q = qb * 64 + qi;
    const float* Qb = Q + (size_t)hb * L * D;
    const float* Kb = K + (size_t)hb * L * D;

    float qrow[D];
#pragma unroll
    for (int d = 0; d < D; d += 4) {
        const float4 v4 = *(const float4*)(Qb + q * D + d);
        qrow[d] = v4.x; qrow[d + 1] = v4.y; qrow[d + 2] = v4.z; qrow[d + 3] = v4.w;
    }

    float l = 0.f;
    for (int tile = 0; tile < 8; ++tile) {
        __syncthreads();
        // cooperative load: 4 regions x (64 keys x 32 f32) = 8192 floats
#pragma unroll
        for (int i = 0; i < 8; ++i) {
            const int idx = i * 1024 + tid * 4;
            const int kg2 = idx >> 11;
            const int rem = idx & 2047;
            *(float4*)(&kt[0][0][0] + kg2 * 2048 + rem) =
                *(const float4*)(Kb + (kg2 * 512 + tile * 64) * D + rem);
        }
        __syncthreads();
#pragma unroll 4
        for (int j = 0; j < 64; ++j) {
            float s = 0.f;
#pragma unroll
            for (int d = 0; d < D; ++d) s += qrow[d] * kt[kg][j][d];
            l += __expf(s);
        }
    }

    lred[kg][qi] = l;
    __syncthreads();
    if (tid < 64) {
        const float lt = lred[0][tid] + lred[1][tid] + lred[2][tid] + lred[3][tid];
        G[hb * L + qb * 64 + tid] = V[hb * L + qb * 64 + tid] / lt;
    }
}

// ---------------------------------------------------------------------------
// Kernel 3 (pass B): S[k] = sum_{q >= k} exp(s_qk) * G[q].
// grid = HB * (L/64) = 512 blocks, 256 threads = 4 waves.
// Wave qg handles query range [qg*512, qg*512+512); lane ki owns key kb*64+ki.
// Wave-uniform skip of tiles fully below the diagonal keeps triangular cost.
// ---------------------------------------------------------------------------
__global__ __launch_bounds__(256) void passB_kernel(
    const float* __restrict__ Q,
    const float* __restrict__ K,
    const float* __restrict__ G,
    float* __restrict__ S)
{
    __shared__ float qt[4][64][D];   // 32 KiB
    __shared__ float gt[4][64];
    __shared__ float sred[4][64];
    const int tid = threadIdx.x;
    const int qg = tid >> 6, ki = tid & 63;
    const int hb = blockIdx.x >> 5;
    const int kb = blockIdx.x & 31;
    const int k = kb * 64 + ki;
    const float* Qb = Q + (size_t)hb * L * D;
    const float* Kb = K + (size_t)hb * L * D;
    const float* Gb = G + hb * L;

    float krow[D];
#pragma unroll
    for (int d = 0; d < D; d += 4) {
        const float4 v4 = *(const float4*)(Kb + k * D + d);
        krow[d] = v4.x; krow[d + 1] = v4.y; krow[d + 2] = v4.z; krow[d + 3] = v4.w;
    }

    float s_acc = 0.f;
    const int kmin = kb * 64;
    for (int tile = 0; tile < 8; ++tile) {
        __syncthreads();
#pragma unroll
        for (int i = 0; i < 8; ++i) {
            const int idx = i * 1024 + tid * 4;
            const int qg2 = idx >> 11;
            const int rem = idx & 2047;
            *(float4*)(&qt[0][0][0] + qg2 * 2048 + rem) =
                *(const float4*)(Qb + (qg2 * 512 + tile * 64) * D + rem);
        }
        {
            const int qg2 = tid >> 6, j = tid & 63;
            gt[qg2][j] = Gb[qg2 * 512 + tile * 64 + j];
        }
        __syncthreads();

        const int q0 = qg * 512 + tile * 64;
        if (q0 + 64 > kmin) {  // wave-uniform triangular skip
#pragma unroll 4
            for (int j = 0; j < 64; ++j) {
                float s = 0.f;
#pragma unroll
                for (int d = 0; d < D; ++d) s += krow[d] * qt[qg][j][d];
                const float p = __expf(s) * gt[qg][j];
                if (q0 + j >= k) s_acc += p;
            }
        }
    }

    sred[qg][ki] = s_acc;
    __syncthreads();
    if (tid < 64) {
        S[hb * L + kb * 64 + tid] =
            sred[0][tid] + sred[1][tid] + sred[2][tid] + sred[3][tid];
    }
}

// ---------------------------------------------------------------------------
// Kernel 4: windowed average along k (W=3, SAME, pad-excluded counts) and
// layout transform to (B, L, H).  grid = B*L*H/256 = 128 blocks.
// ---------------------------------------------------------------------------
__global__ __launch_bounds__(256) void pool_kernel(
    const float* __restrict__ S, float* __restrict__ out)
{
    const int flat = blockIdx.x * 256 + threadIdx.x;  // (b*L + k)*H + h
    const int h = flat & 7;
    const int k = (flat >> 3) & (L - 1);
    const int b = flat >> 14;
    const float* Sb = S + (h * B + b) * L;
    float s = Sb[k];
    float cnt = 1.f;
    if (k > 0)     { s += Sb[k - 1]; cnt += 1.f; }
    if (k < L - 1) { s += Sb[k + 1]; cnt += 1.f; }
    out[flat] = s / cnt;
}

// ---------------------------------------------------------------------------
extern "C" void kernel_launch(void* const* d_in, const int* in_sizes, int n_in,
                              void* d_out, int out_size, void* d_ws, size_t ws_size,
                              hipStream_t stream)
{
    const float* x  = (const float*)d_in[0];
    const float* Wq = (const float*)d_in[1];
    const float* bq = (const float*)d_in[2];
    const float* Wk = (const float*)d_in[3];
    const float* bk = (const float*)d_in[4];
    const float* Wv = (const float*)d_in[5];
    const float* pe = (const float*)d_in[6];
    float* out = (float*)d_out;

    float* Qo = (float*)d_ws;                       // H*B*L*D = 1,048,576 f32
    float* Ko = Qo + (size_t)H * B * L * D;         // 1,048,576 f32
    float* Vo = Ko + (size_t)H * B * L * D;         // 32,768 f32
    float* G  = Vo + (size_t)H * B * L;             // 32,768 f32
    float* S  = G  + (size_t)H * B * L;             // 32,768 f32

    proj_kernel<<<B * L / 16, 256, 0, stream>>>(x, Wq, bq, Wk, bk, Wv, pe, Qo, Ko, Vo);
    passA_kernel<<<HB * (L / 64), 256, 0, stream>>>(Qo, Ko, Vo, G);
    passB_kernel<<<HB * (L / 64), 256, 0, stream>>>(Qo, Ko, G, S);
    pool_kernel<<<(B * L * H) / 256, 256, 0, stream>>>(S, out);
}

// Round 2
// 141.240 us; speedup vs baseline: 2.8432x; 2.8432x over previous
//
#include <hip/hip_runtime.h>

#define B 2
#define L 2048
#define C 256
#define H 8
#define D 32
#define HB (H * H / 4)  // 16 = H*B
#define SCALE 0.17677669529663687f  // 1/sqrt(32)

using bf16x8 = __attribute__((ext_vector_type(8))) __bf16;
using f32x4  = __attribute__((ext_vector_type(4))) float;

// round-to-nearest-even f32 -> bf16 bits
static __device__ inline unsigned short f2bf(float f) {
    unsigned u = __float_as_uint(f);
    return (unsigned short)((u + 0x7fffu + ((u >> 16) & 1u)) >> 16);
}

// ---------------------------------------------------------------------------
// Kernel 1: projections. grid = B*L/8 = 512 blocks, 256 threads (4 waves).
// 8 rows/block; x-tile stored TRANSPOSED in LDS so the per-channel broadcast
// read is 2x ds_read_b128 instead of 8x ds_read_b32.
// Emits Q (pre-scaled by 1/sqrt(D)) and K as bf16 rows (hb, l, 32) for MFMA.
// ---------------------------------------------------------------------------
__global__ __launch_bounds__(256) void proj_kernel(
    const float* __restrict__ x,   // (B,L,C)
    const float* __restrict__ Wq,  // (C, H*D)
    const float* __restrict__ bq,  // (H,1,1,D) flat = h*D+d
    const float* __restrict__ Wk,
    const float* __restrict__ bk,
    const float* __restrict__ Wv,  // (C, H)
    const float* __restrict__ pe,  // (L, C)
    unsigned short* __restrict__ Qo,  // (HB, L, D) bf16 bits
    unsigned short* __restrict__ Ko,  // (HB, L, D) bf16 bits
    float* __restrict__ Vo)           // (HB, L)
{
    __shared__ float xqT[C][8];   // transposed: [channel][row]
    __shared__ float xrT[C][8];
    __shared__ float vred[4][8][8];
    const int t = threadIdx.x;
    const int row0 = blockIdx.x * 8;
    const int b = row0 >> 11;          // 8-row block never straddles batches

#pragma unroll
    for (int i = 0; i < 8; ++i) {
        const int row = row0 + i;
        const int l = row & (L - 1);
        const float xv = x[row * C + t];
        xrT[t][i] = xv;
        xqT[t][i] = xv + pe[l * C + t];
    }
    __syncthreads();

    float accq[8], acck[8];
#pragma unroll
    for (int i = 0; i < 8; ++i) { accq[i] = 0.f; acck[i] = 0.f; }

#pragma unroll 4
    for (int c = 0; c < C; ++c) {
        const float wq = Wq[c * (H * D) + t];
        const float wk = Wk[c * (H * D) + t];
        const float4 xa = *(const float4*)&xqT[c][0];
        const float4 xb = *(const float4*)&xqT[c][4];
        accq[0] += xa.x * wq; acck[0] += xa.x * wk;
        accq[1] += xa.y * wq; acck[1] += xa.y * wk;
        accq[2] += xa.z * wq; acck[2] += xa.z * wk;
        accq[3] += xa.w * wq; acck[3] += xa.w * wk;
        accq[4] += xb.x * wq; acck[4] += xb.x * wk;
        accq[5] += xb.y * wq; acck[5] += xb.y * wk;
        accq[6] += xb.z * wq; acck[6] += xb.z * wk;
        accq[7] += xb.w * wq; acck[7] += xb.w * wk;
    }

    const int h = t >> 5, d = t & 31;
    const float bqv = bq[t];
    const float bkv = bk[t];
#pragma unroll
    for (int i = 0; i < 8; ++i) {
        const int l = (row0 + i) & (L - 1);
        const size_t o = ((size_t)(h * B + b) * L + l) * D + d;
        Qo[o] = f2bf((accq[i] + bqv) * SCALE);
        Ko[o] = f2bf(acck[i] + bkv);
    }

    // V gate: split C into 4 chunks across the 4 waves, LDS-reduce.
    {
        const int cc = t >> 6, sub = t & 63, vi = sub >> 3, vh = sub & 7;
        float va = 0.f;
        for (int c = cc * 64; c < cc * 64 + 64; ++c)
            va += xrT[c][vi] * Wv[c * H + vh];
        vred[cc][vi][vh] = va;
    }
    __syncthreads();
    if (t < 64) {
        const int i2 = t >> 3, h2 = t & 7;
        const float v = vred[0][i2][h2] + vred[1][i2][h2] +
                        vred[2][i2][h2] + vred[3][i2][h2];
        const int l = (row0 + i2) & (L - 1);
        Vo[(h2 * B + b) * L + l] = v;
    }
}

// ---------------------------------------------------------------------------
// Kernel 2 (pass A): l_q = sum_k exp(s_qk) over ALL k (mask comes after
// softmax in the reference), G[q] = V[q] / l_q.
// grid = HB * (L/16) = 2048 blocks, 4 waves; block owns one 16-query tile,
// waves split the key range 4 ways. Fragments loaded straight from global
// (L2-resident, 16B/lane coalesced) -- no LDS staging.
// A-frag: Q[q = qt*16 + (lane&15)][d = (lane>>4)*8 + j]
// B-frag: K[k = kt*16 + (lane&15)][d = (lane>>4)*8 + j]
// C/D:    col(lane&15)=k, row((lane>>4)*4+reg)=q   [m89/m91 verified]
// ---------------------------------------------------------------------------
__global__ __launch_bounds__(256) void passA_kernel(
    const __bf16* __restrict__ Qb, const __bf16* __restrict__ Kb,
    const float* __restrict__ V, float* __restrict__ G)
{
    __shared__ float lred[4][4][4][16];  // [wave][quad][reg r][col]
    const int tid = threadIdx.x;
    const int w = tid >> 6, lane = tid & 63;
    const int quad = lane >> 4, col = lane & 15;
    const int qt = blockIdx.x & 127, hb = blockIdx.x >> 7;
    const __bf16* Qp = Qb + (size_t)hb * L * D;
    const __bf16* Kp = Kb + (size_t)hb * L * D;

    const bf16x8 qf = *(const bf16x8*)(Qp + (qt * 16 + col) * D + quad * 8);
    const f32x4 zero = {0.f, 0.f, 0.f, 0.f};

    float l0 = 0.f, l1 = 0.f, l2 = 0.f, l3 = 0.f;
    const int t0 = w * 32;  // 32 key-tiles (512 keys) per wave
#pragma unroll 4
    for (int kt = 0; kt < 32; ++kt) {
        const bf16x8 kf =
            *(const bf16x8*)(Kp + ((t0 + kt) * 16 + col) * D + quad * 8);
        f32x4 a = __builtin_amdgcn_mfma_f32_16x16x32_bf16(qf, kf, zero, 0, 0, 0);
        l0 += __expf(a[0]);
        l1 += __expf(a[1]);
        l2 += __expf(a[2]);
        l3 += __expf(a[3]);
    }
    lred[w][quad][0][col] = l0;
    lred[w][quad][1][col] = l1;
    lred[w][quad][2][col] = l2;
    lred[w][quad][3][col] = l3;
    __syncthreads();
    if (tid < 16) {  // q row = quad*4 + r = tid
        const int qd = tid >> 2, r = tid & 3;
        float s = 0.f;
#pragma unroll
        for (int w2 = 0; w2 < 4; ++w2) {
            const float* p = &lred[w2][qd][r][0];
#pragma unroll
            for (int c2 = 0; c2 < 16; ++c2) s += p[c2];
        }
        const int qq = hb * L + qt * 16 + tid;
        G[qq] = V[qq] / s;
    }
}

// ---------------------------------------------------------------------------
// Kernel 3 (pass B): S[k] = sum_{q >= k} G[q] * exp(s_qk).
// grid = HB * (L/16) = 2048 blocks; block owns one 16-key tile (B-fragment
// loaded once), waves interleave over q-tiles >= the diagonal.
// ---------------------------------------------------------------------------
__global__ __launch_bounds__(256) void passB_kernel(
    const __bf16* __restrict__ Qb, const __bf16* __restrict__ Kb,
    const float* __restrict__ G, float* __restrict__ S)
{
    __shared__ float sred[4][4][16];  // [wave][quad][col]
    const int tid = threadIdx.x;
    const int w = tid >> 6, lane = tid & 63;
    const int quad = lane >> 4, col = lane & 15;
    const int kb = blockIdx.x & 127, hb = blockIdx.x >> 7;
    const __bf16* Qp = Qb + (size_t)hb * L * D;
    const __bf16* Kp = Kb + (size_t)hb * L * D;
    const float* Gp = G + hb * L;

    const bf16x8 kf = *(const bf16x8*)(Kp + (kb * 16 + col) * D + quad * 8);
    const f32x4 zero = {0.f, 0.f, 0.f, 0.f};
    const int kidx = kb * 16 + col;

    float sacc = 0.f;
    for (int qt = kb + w; qt < 128; qt += 4) {
        const bf16x8 qf =
            *(const bf16x8*)(Qp + (qt * 16 + col) * D + quad * 8);
        f32x4 a = __builtin_amdgcn_mfma_f32_16x16x32_bf16(qf, kf, zero, 0, 0, 0);
        const float4 g = *(const float4*)(Gp + qt * 16 + quad * 4);
        const int qbase = qt * 16 + quad * 4;
        sacc += (qbase + 0 >= kidx) ? __expf(a[0]) * g.x : 0.f;
        sacc += (qbase + 1 >= kidx) ? __expf(a[1]) * g.y : 0.f;
        sacc += (qbase + 2 >= kidx) ? __expf(a[2]) * g.z : 0.f;
        sacc += (qbase + 3 >= kidx) ? __expf(a[3]) * g.w : 0.f;
    }
    sred[w][quad][col] = sacc;
    __syncthreads();
    if (tid < 16) {
        float s = 0.f;
#pragma unroll
        for (int w2 = 0; w2 < 4; ++w2)
#pragma unroll
            for (int q2 = 0; q2 < 4; ++q2) s += sred[w2][q2][tid];
        S[hb * L + kb * 16 + tid] = s;
    }
}

// ---------------------------------------------------------------------------
// Kernel 4: windowed average along k (W=3, SAME, pad-excluded counts) and
// layout transform to (B, L, H).
// ---------------------------------------------------------------------------
__global__ __launch_bounds__(256) void pool_kernel(
    const float* __restrict__ S, float* __restrict__ out)
{
    const int flat = blockIdx.x * 256 + threadIdx.x;  // (b*L + k)*H + h
    const int h = flat & 7;
    const int k = (flat >> 3) & (L - 1);
    const int b = flat >> 14;
    const float* Sb = S + (h * B + b) * L;
    float s = Sb[k];
    float cnt = 1.f;
    if (k > 0)     { s += Sb[k - 1]; cnt += 1.f; }
    if (k < L - 1) { s += Sb[k + 1]; cnt += 1.f; }
    out[flat] = s / cnt;
}

// ---------------------------------------------------------------------------
extern "C" void kernel_launch(void* const* d_in, const int* in_sizes, int n_in,
                              void* d_out, int out_size, void* d_ws, size_t ws_size,
                              hipStream_t stream)
{
    const float* x  = (const float*)d_in[0];
    const float* Wq = (const float*)d_in[1];
    const float* bq = (const float*)d_in[2];
    const float* Wk = (const float*)d_in[3];
    const float* bk = (const float*)d_in[4];
    const float* Wv = (const float*)d_in[5];
    const float* pe = (const float*)d_in[6];
    float* out = (float*)d_out;

    unsigned short* Qbf = (unsigned short*)d_ws;          // 16*2048*32 = 1,048,576 elems (2 MB)
    unsigned short* Kbf = Qbf + (size_t)HB * L * D;       // 2 MB
    float* Vo = (float*)(Kbf + (size_t)HB * L * D);       // 32768 f32
    float* G  = Vo + (size_t)HB * L;                      // 32768 f32
    float* S  = G  + (size_t)HB * L;                      // 32768 f32

    proj_kernel<<<B * L / 8, 256, 0, stream>>>(x, Wq, bq, Wk, bk, Wv, pe,
                                               Qbf, Kbf, Vo);
    passA_kernel<<<HB * (L / 16), 256, 0, stream>>>(
        (const __bf16*)Qbf, (const __bf16*)Kbf, Vo, G);
    passB_kernel<<<HB * (L / 16), 256, 0, stream>>>(
        (const __bf16*)Qbf, (const __bf16*)Kbf, G, S);
    pool_kernel<<<(B * L * H) / 256, 256, 0, stream>>>(S, out);
}